// Round 3
// baseline (700.895 us; speedup 1.0000x reference)
//
#include <hip/hip_runtime.h>

#define B_SZ 4096
#define E_EXP 20
#define NE 21  // 20 experts + gate share the trunk

typedef unsigned short u16;
typedef __bf16 bf16x8 __attribute__((ext_vector_type(8)));
typedef u16 u16x8 __attribute__((ext_vector_type(8)));
typedef u16 u16x4 __attribute__((ext_vector_type(4)));
typedef float floatx4 __attribute__((ext_vector_type(4)));

static __device__ __forceinline__ u16 f2bf(float f) {
  unsigned u = __builtin_bit_cast(unsigned, f);
  u += 0x7fffu + ((u >> 16) & 1u);  // RNE
  return (u16)(u >> 16);
}

static __device__ __forceinline__ float elu1(float v) {
  return v > 0.f ? v : (__expf(v) - 1.f);
}

static __device__ __forceinline__ bf16x8 ld_bf8(const u16* p) {
  u16x8 v = *reinterpret_cast<const u16x8*>(p);
  return __builtin_bit_cast(bf16x8, v);
}

// async global->LDS DMA, 16B per lane. LDS dest is wave-uniform base +
// lane*16 — lds ptr must be linear in thread order (no padding!).
static __device__ __forceinline__ void gld_lds16(const u16* g, u16* l) {
  __builtin_amdgcn_global_load_lds(
      (const __attribute__((address_space(1))) unsigned int*)g,
      (__attribute__((address_space(3))) unsigned int*)l, 16, 0, 0);
}

// ---------------- conversion kernels ----------------

__global__ void convert_obs_kernel(const float* __restrict__ src,
                                   u16* __restrict__ dst, int n) {
  int i = (blockIdx.x * blockDim.x + threadIdx.x) * 4;
  if (i < n) {
    float4 v = *reinterpret_cast<const float4*>(src + i);
    u16x4 o;
    o.x = f2bf(v.x); o.y = f2bf(v.y); o.z = f2bf(v.z); o.w = f2bf(v.w);
    *reinterpret_cast<u16x4*>(dst + i) = o;
  }
}

// W [K,N] fp32 -> Wt [N(out-padded),K] bf16, per blockIdx.z matrix.
__global__ void transpose_conv_kernel(const float* __restrict__ src_e,
                                      const float* __restrict__ src_g,
                                      int n_e, int K, int N, int Nout,
                                      u16* __restrict__ dst) {
  int e = blockIdx.z;
  const float* src = (e < n_e) ? (src_e + (long)e * K * N) : src_g;
  __shared__ float tile[32][33];
  int tx = threadIdx.x & 31;
  int ty = threadIdx.x >> 5;  // 0..7
  int kbase = blockIdx.x * 32;
  int nbase = blockIdx.y * 32;
#pragma unroll
  for (int i = 0; i < 4; ++i) {
    int k = kbase + ty + i * 8;
    int n = nbase + tx;
    float v = 0.f;
    if (k < K && n < N) v = src[(long)k * N + n];
    tile[ty + i * 8][tx] = v;
  }
  __syncthreads();
  u16* dstE = dst + (long)e * Nout * K;
#pragma unroll
  for (int i = 0; i < 4; ++i) {
    int n = nbase + ty + i * 8;
    int k = kbase + tx;
    if (n < Nout && k < K) dstE[(long)n * K + k] = f2bf(tile[tx][ty + i * 8]);
  }
}

// concat [E,H] expert biases + [H] gate bias -> [E+1,H]
__global__ void concat_bias_kernel(const float* __restrict__ e_b,
                                   const float* __restrict__ g_b,
                                   int E, int H, float* __restrict__ dst) {
  int i = blockIdx.x * blockDim.x + threadIdx.x;
  int total = (E + 1) * H;
  if (i < total) dst[i] = (i < E * H) ? e_b[i] : g_b[i - E * H];
}

// ---------------- grouped GEMM + bias + ELU ----------------
// C[M,N] = elu(A[M,K] @ Wt[N,K]^T + bias), bf16 in/out, fp32 accumulate.
// blockIdx.z = expert; blockIdx.x = n-stripe (held fixed; W tile stays
// L2-hot); block loops m-tiles strided by gridDim.y.
// MFMA operands SWAPPED (W = A-operand): D row-dim -> n, col-dim -> m,
// so each lane holds 4 consecutive n -> packed u16x4 stores.

#define BM 128
#define BN 128
#define BK 32

__global__ __launch_bounds__(256) void gemm_bias_elu_kernel(
    const u16* __restrict__ A_base, long a_estride,
    const u16* __restrict__ Wt_base, long w_estride,
    const float* __restrict__ bias_base, long b_estride,
    u16* __restrict__ C_base, long c_estride,
    int M, int N, int K) {
  int e = blockIdx.z;
  const u16* A = A_base + (long)e * a_estride;
  const u16* Wt = Wt_base + (long)e * w_estride;
  const float* bias = bias_base + (long)e * b_estride;
  u16* C = C_base + (long)e * c_estride;

  int n0 = blockIdx.x * BN;

  // unpadded: required by global_load_lds (lane-linear dest)
  __shared__ u16 As[BM * BK];
  __shared__ u16 Bs[BN * BK];

  int tid = threadIdx.x;
  int lane = tid & 63;
  int w = tid >> 6;            // wave 0..3 in 2x2
  int wm = (w >> 1) * 64;
  int wn = (w & 1) * 64;
  int col = lane & 15;
  int quad = lane >> 4;

  // staging map: idx = s*256+tid covers LDS bytes [idx*16, idx*16+16)
  int srow = tid >> 2;         // 0..63
  int scol = (tid & 3) * 8;    // 0,8,16,24
  const u16* gb0 = &Wt[(long)(n0 + srow) * K + scol];
  const u16* gb1 = &Wt[(long)(n0 + 64 + srow) * K + scol];
  u16* la0 = &As[(size_t)tid * 8];
  u16* la1 = &As[(size_t)(256 + tid) * 8];
  u16* lb0 = &Bs[(size_t)tid * 8];
  u16* lb1 = &Bs[(size_t)(256 + tid) * 8];

  int mtiles = M / BM;
  for (int mt = blockIdx.y; mt < mtiles; mt += gridDim.y) {
    int m0 = mt * BM;
    const u16* ga0 = &A[(long)(m0 + srow) * K + scol];
    const u16* ga1 = &A[(long)(m0 + 64 + srow) * K + scol];

    floatx4 acc[4][4] = {};

    for (int k0 = 0; k0 < K; k0 += BK) {
      __syncthreads();  // prior LDS reads done before overwrite
      gld_lds16(ga0 + k0, la0);
      gld_lds16(ga1 + k0, la1);
      gld_lds16(gb0 + k0, lb0);
      gld_lds16(gb1 + k0, lb1);
      __syncthreads();  // drains vmcnt -> staged data visible

      bf16x8 xf[4], wf[4];
#pragma unroll
      for (int t = 0; t < 4; ++t) {
        xf[t] = __builtin_bit_cast(bf16x8,
            *reinterpret_cast<u16x8*>(&As[(wm + t * 16 + col) * BK + quad * 8]));
        wf[t] = __builtin_bit_cast(bf16x8,
            *reinterpret_cast<u16x8*>(&Bs[(wn + t * 16 + col) * BK + quad * 8]));
      }
#pragma unroll
      for (int i = 0; i < 4; ++i)
#pragma unroll
        for (int j = 0; j < 4; ++j)
          acc[i][j] = __builtin_amdgcn_mfma_f32_16x16x32_bf16(
              wf[j], xf[i], acc[i][j], 0, 0, 0);
    }

    // epilogue: lane holds m = m0+wm+i*16+col, n = n0+wn+j*16+quad*4+[0..3]
#pragma unroll
    for (int j = 0; j < 4; ++j) {
      int nn = n0 + wn + j * 16 + quad * 4;
      float4 b4 = *reinterpret_cast<const float4*>(&bias[nn]);
#pragma unroll
      for (int i = 0; i < 4; ++i) {
        int m = m0 + wm + i * 16 + col;
        u16x4 o;
        o.x = f2bf(elu1(acc[i][j][0] + b4.x));
        o.y = f2bf(elu1(acc[i][j][1] + b4.y));
        o.z = f2bf(elu1(acc[i][j][2] + b4.z));
        o.w = f2bf(elu1(acc[i][j][3] + b4.w));
        *reinterpret_cast<u16x4*>(&C[(long)m * N + nn]) = o;
      }
    }
  }
}

// ---------------- fused L4: gate head + softmax + expert heads + combine ----
__global__ __launch_bounds__(64) void final_combine_kernel(
    const u16* __restrict__ h3, const u16* __restrict__ W4t,
    const u16* __restrict__ gW4t, const float* __restrict__ eb4,
    const float* __restrict__ gb4, float* __restrict__ out) {
  const int H3 = 256;
  int lane = threadIdx.x;
  int col = lane & 15;
  int quad = lane >> 4;
  int r0 = blockIdx.x * 16;

  // ---- gate logits ----
  floatx4 g0 = {}, g1 = {};
  const u16* h3g = h3 + (long)E_EXP * B_SZ * H3;
#pragma unroll
  for (int k0 = 0; k0 < 256; k0 += 32) {
    bf16x8 a = ld_bf8(&h3g[(long)(r0 + col) * H3 + k0 + quad * 8]);
    bf16x8 b0 = ld_bf8(&gW4t[(long)col * H3 + k0 + quad * 8]);
    bf16x8 b1 = ld_bf8(&gW4t[(long)(16 + col) * H3 + k0 + quad * 8]);
    g0 = __builtin_amdgcn_mfma_f32_16x16x32_bf16(a, b0, g0, 0, 0, 0);
    g1 = __builtin_amdgcn_mfma_f32_16x16x32_bf16(a, b1, g1, 0, 0, 0);
  }

  // ---- softmax over 20 logits per row ----
  float w0[4], w1[4];
  float gbc0 = gb4[col];
  float gbc1 = (col < 4) ? gb4[16 + col] : 0.f;
#pragma unroll
  for (int r = 0; r < 4; ++r) {
    float v0 = g0[r] + gbc0;
    float v1 = (col < 4) ? (g1[r] + gbc1) : -1e30f;
    float m = fmaxf(v0, v1);
#pragma unroll
    for (int s = 1; s < 16; s <<= 1) m = fmaxf(m, __shfl_xor(m, s, 64));
    float e0 = __expf(v0 - m);
    float e1 = (col < 4) ? __expf(v1 - m) : 0.f;
    float ssum = e0 + e1;
#pragma unroll
    for (int s = 1; s < 16; s <<= 1) ssum += __shfl_xor(ssum, s, 64);
    w0[r] = e0 / ssum;
    w1[r] = e1 / ssum;
  }

  // ---- expert heads + weighted combine ----
  floatx4 o0 = {}, o1 = {};
  for (int e = 0; e < E_EXP; ++e) {
    floatx4 a0 = {}, a1 = {};
    const u16* he = h3 + (long)e * B_SZ * H3;
    const u16* we = W4t + (long)e * 32 * H3;
#pragma unroll
    for (int k0 = 0; k0 < 256; k0 += 32) {
      bf16x8 a = ld_bf8(&he[(long)(r0 + col) * H3 + k0 + quad * 8]);
      bf16x8 b0 = ld_bf8(&we[(long)col * H3 + k0 + quad * 8]);
      bf16x8 b1 = ld_bf8(&we[(long)(16 + col) * H3 + k0 + quad * 8]);
      a0 = __builtin_amdgcn_mfma_f32_16x16x32_bf16(a, b0, a0, 0, 0, 0);
      a1 = __builtin_amdgcn_mfma_f32_16x16x32_bf16(a, b1, a1, 0, 0, 0);
    }
    float be0 = eb4[e * 32 + col];
    float be1 = eb4[e * 32 + 16 + col];
    int src = (lane & 48) + (e & 15);
#pragma unroll
    for (int r = 0; r < 4; ++r) {
      float wr = __shfl((e < 16) ? w0[r] : w1[r], src, 64);
      o0[r] += wr * (a0[r] + be0);
      o1[r] += wr * (a1[r] + be1);
    }
  }
#pragma unroll
  for (int r = 0; r < 4; ++r) {
    int row = r0 + quad * 4 + r;
    out[(long)row * 32 + col] = o0[r];
    out[(long)row * 32 + 16 + col] = o1[r];
  }
}

// ---------------- host launch ----------------

static inline size_t align256(size_t x) { return (x + 255) & ~(size_t)255; }

extern "C" void kernel_launch(void* const* d_in, const int* in_sizes, int n_in,
                              void* d_out, int out_size, void* d_ws,
                              size_t ws_size, hipStream_t stream) {
  const float* obs = (const float*)d_in[0];
  const float* eW1 = (const float*)d_in[1];
  const float* eb1 = (const float*)d_in[2];
  const float* eW2 = (const float*)d_in[3];
  const float* eb2 = (const float*)d_in[4];
  const float* eW3 = (const float*)d_in[5];
  const float* eb3 = (const float*)d_in[6];
  const float* eW4 = (const float*)d_in[7];
  const float* eb4 = (const float*)d_in[8];
  const float* gW1 = (const float*)d_in[9];
  const float* gb1 = (const float*)d_in[10];
  const float* gW2 = (const float*)d_in[11];
  const float* gb2 = (const float*)d_in[12];
  const float* gW3 = (const float*)d_in[13];
  const float* gb3 = (const float*)d_in[14];
  const float* gW4 = (const float*)d_in[15];
  const float* gb4 = (const float*)d_in[16];
  float* out = (float*)d_out;
  char* ws = (char*)d_ws;

  // fixed workspace region
  size_t off = 0;
  size_t OFF_OBS = off;  off = align256(off + (size_t)B_SZ * 512 * 2);
  size_t OFF_W1T = off;  off = align256(off + (size_t)NE * 1024 * 512 * 2);
  size_t OFF_W2T = off;  off = align256(off + (size_t)NE * 512 * 1024 * 2);
  size_t OFF_W3T = off;  off = align256(off + (size_t)NE * 256 * 512 * 2);
  size_t OFF_W4T = off;  off = align256(off + (size_t)E_EXP * 32 * 256 * 2);
  size_t OFF_GW4T = off; off = align256(off + (size_t)32 * 256 * 2);
  size_t OFF_B1 = off;   off = align256(off + (size_t)NE * 1024 * 4);
  size_t OFF_B2 = off;   off = align256(off + (size_t)NE * 512 * 4);
  size_t OFF_B3 = off;   off = align256(off + (size_t)NE * 256 * 4);
  size_t OFF_H3 = off;   off = align256(off + (size_t)NE * B_SZ * 256 * 2);

  // adaptive batch-chunked h1/h2: every dispatch covers all 21 experts
  int chunk = B_SZ;
  size_t OFF_H1 = off;
  while (chunk > 512) {
    size_t need = (size_t)NE * chunk * 1024 * 2 + (size_t)NE * chunk * 512 * 2;
    if (OFF_H1 + need <= ws_size) break;
    chunk >>= 1;
  }
  size_t OFF_H2 = align256(OFF_H1 + (size_t)NE * chunk * 1024 * 2);

  u16* obs_bf = (u16*)(ws + OFF_OBS);
  u16* W1t = (u16*)(ws + OFF_W1T);
  u16* W2t = (u16*)(ws + OFF_W2T);
  u16* W3t = (u16*)(ws + OFF_W3T);
  u16* W4t = (u16*)(ws + OFF_W4T);
  u16* gW4t = (u16*)(ws + OFF_GW4T);
  float* b1 = (float*)(ws + OFF_B1);
  float* b2 = (float*)(ws + OFF_B2);
  float* b3 = (float*)(ws + OFF_B3);
  u16* h3 = (u16*)(ws + OFF_H3);
  u16* h1 = (u16*)(ws + OFF_H1);
  u16* h2 = (u16*)(ws + OFF_H2);

  // --- conversions ---
  convert_obs_kernel<<<(B_SZ * 512 / 4 + 255) / 256, 256, 0, stream>>>(
      obs, obs_bf, B_SZ * 512);
  transpose_conv_kernel<<<dim3(16, 32, NE), 256, 0, stream>>>(
      eW1, gW1, E_EXP, 512, 1024, 1024, W1t);
  transpose_conv_kernel<<<dim3(32, 16, NE), 256, 0, stream>>>(
      eW2, gW2, E_EXP, 1024, 512, 512, W2t);
  transpose_conv_kernel<<<dim3(16, 8, NE), 256, 0, stream>>>(
      eW3, gW3, E_EXP, 512, 256, 256, W3t);
  transpose_conv_kernel<<<dim3(8, 1, E_EXP), 256, 0, stream>>>(
      eW4, nullptr, E_EXP, 256, 32, 32, W4t);
  transpose_conv_kernel<<<dim3(8, 1, 1), 256, 0, stream>>>(
      gW4, nullptr, 1, 256, 20, 32, gW4t);
  concat_bias_kernel<<<(NE * 1024 + 255) / 256, 256, 0, stream>>>(
      eb1, gb1, E_EXP, 1024, b1);
  concat_bias_kernel<<<(NE * 512 + 255) / 256, 256, 0, stream>>>(
      eb2, gb2, E_EXP, 512, b2);
  concat_bias_kernel<<<(NE * 256 + 255) / 256, 256, 0, stream>>>(
      eb3, gb3, E_EXP, 256, b3);

  int mtiles = chunk / BM;
  int ms1 = mtiles < 4 ? mtiles : 4;
  int ms2 = mtiles < 4 ? mtiles : 4;
  int ms3 = mtiles < 8 ? mtiles : 8;

  // --- trunk layers 1..3, batch-chunked, all experts per dispatch ---
  for (int bc = 0; bc < B_SZ; bc += chunk) {
    gemm_bias_elu_kernel<<<dim3(1024 / BN, ms1, NE), 256, 0, stream>>>(
        obs_bf + (size_t)bc * 512, 0L,
        W1t, (long)1024 * 512,
        b1, 1024L,
        h1, (long)chunk * 1024, chunk, 1024, 512);
    gemm_bias_elu_kernel<<<dim3(512 / BN, ms2, NE), 256, 0, stream>>>(
        h1, (long)chunk * 1024,
        W2t, (long)512 * 1024,
        b2, 512L,
        h2, (long)chunk * 512, chunk, 512, 1024);
    gemm_bias_elu_kernel<<<dim3(256 / BN, ms3, NE), 256, 0, stream>>>(
        h2, (long)chunk * 512,
        W3t, (long)256 * 512,
        b3, 256L,
        h3 + (size_t)bc * 256, (long)B_SZ * 256, chunk, 256, 512);
  }

  // --- fused layer-4 + softmax + combine ---
  final_combine_kernel<<<B_SZ / 16, 64, 0, stream>>>(h3, W4t, gW4t, eb4, gb4,
                                                     out);
}

// Round 4
// 567.188 us; speedup vs baseline: 1.2357x; 1.2357x over previous
//
#include <hip/hip_runtime.h>

#define B_SZ 4096
#define E_EXP 20
#define NE 21  // 20 experts + gate share the trunk

typedef unsigned short u16;
typedef __bf16 bf16x8 __attribute__((ext_vector_type(8)));
typedef u16 u16x8 __attribute__((ext_vector_type(8)));
typedef u16 u16x4 __attribute__((ext_vector_type(4)));
typedef float floatx4 __attribute__((ext_vector_type(4)));

static __device__ __forceinline__ u16 f2bf(float f) {
  unsigned u = __builtin_bit_cast(unsigned, f);
  u += 0x7fffu + ((u >> 16) & 1u);  // RNE
  return (u16)(u >> 16);
}

static __device__ __forceinline__ float elu1(float v) {
  return v > 0.f ? v : (__expf(v) - 1.f);
}

static __device__ __forceinline__ bf16x8 ld_bf8(const u16* p) {
  u16x8 v = *reinterpret_cast<const u16x8*>(p);
  return __builtin_bit_cast(bf16x8, v);
}

// async global->LDS DMA, 16B per lane. LDS dest is wave-uniform base +
// lane*16 — lds ptr must be linear in thread order (no padding!).
static __device__ __forceinline__ void gld_lds16(const u16* g, u16* l) {
  __builtin_amdgcn_global_load_lds(
      (const __attribute__((address_space(1))) unsigned int*)g,
      (__attribute__((address_space(3))) unsigned int*)l, 16, 0, 0);
}

// ---------------- conversion kernels ----------------

__global__ void convert_obs_kernel(const float* __restrict__ src,
                                   u16* __restrict__ dst, int n) {
  int i = (blockIdx.x * blockDim.x + threadIdx.x) * 4;
  if (i < n) {
    float4 v = *reinterpret_cast<const float4*>(src + i);
    u16x4 o;
    o.x = f2bf(v.x); o.y = f2bf(v.y); o.z = f2bf(v.z); o.w = f2bf(v.w);
    *reinterpret_cast<u16x4*>(dst + i) = o;
  }
}

// W [K,N] fp32 -> Wt [N(out-padded),K] bf16, per blockIdx.z matrix.
__global__ void transpose_conv_kernel(const float* __restrict__ src_e,
                                      const float* __restrict__ src_g,
                                      int n_e, int K, int N, int Nout,
                                      u16* __restrict__ dst) {
  int e = blockIdx.z;
  const float* src = (e < n_e) ? (src_e + (long)e * K * N) : src_g;
  __shared__ float tile[32][33];
  int tx = threadIdx.x & 31;
  int ty = threadIdx.x >> 5;  // 0..7
  int kbase = blockIdx.x * 32;
  int nbase = blockIdx.y * 32;
#pragma unroll
  for (int i = 0; i < 4; ++i) {
    int k = kbase + ty + i * 8;
    int n = nbase + tx;
    float v = 0.f;
    if (k < K && n < N) v = src[(long)k * N + n];
    tile[ty + i * 8][tx] = v;
  }
  __syncthreads();
  u16* dstE = dst + (long)e * Nout * K;
#pragma unroll
  for (int i = 0; i < 4; ++i) {
    int n = nbase + ty + i * 8;
    int k = kbase + tx;
    if (n < Nout && k < K) dstE[(long)n * K + k] = f2bf(tile[tx][ty + i * 8]);
  }
}

// concat [E,H] expert biases + [H] gate bias -> [E+1,H]
__global__ void concat_bias_kernel(const float* __restrict__ e_b,
                                   const float* __restrict__ g_b,
                                   int E, int H, float* __restrict__ dst) {
  int i = blockIdx.x * blockDim.x + threadIdx.x;
  int total = (E + 1) * H;
  if (i < total) dst[i] = (i < E * H) ? e_b[i] : g_b[i - E * H];
}

// ---------------- grouped GEMM + bias + ELU ----------------
// C[M,N] = elu(A[M,K] @ Wt[N,K]^T + bias), bf16 in/out, fp32 accumulate.
// One (m,n) tile per block (full grid — R3 showed persistence kills
// occupancy + L2 reuse). BK=64 staged as TWO 32-wide panels per barrier
// pair: halves barrier count, keeps the bank-balanced 64B row stride.
// MFMA operands SWAPPED (W = A-operand): lane holds 4 consecutive n ->
// packed u16x4 stores, float4 bias loads.

#define BM 128
#define BN 128

__global__ __launch_bounds__(256) void gemm_bias_elu_kernel(
    const u16* __restrict__ A_base, long a_estride,
    const u16* __restrict__ Wt_base, long w_estride,
    const float* __restrict__ bias_base, long b_estride,
    u16* __restrict__ C_base, long c_estride,
    int M, int N, int K) {
  int e = blockIdx.z;
  const u16* A = A_base + (long)e * a_estride;
  const u16* Wt = Wt_base + (long)e * w_estride;
  const float* bias = bias_base + (long)e * b_estride;
  u16* C = C_base + (long)e * c_estride;

  int m0 = blockIdx.y * BM;
  int n0 = blockIdx.x * BN;

  // [panel][row][32] — lane-linear for global_load_lds (no padding)
  __shared__ u16 As[2 * BM * 32];
  __shared__ u16 Bs[2 * BN * 32];

  int tid = threadIdx.x;
  int lane = tid & 63;
  int w = tid >> 6;            // wave 0..3 in 2x2
  int wm = (w >> 1) * 64;
  int wn = (w & 1) * 64;
  int col = lane & 15;
  int quad = lane >> 4;

  floatx4 acc[4][4] = {};

  // staging: issue s covers LDS chunks [s*256+tid]*16B
  //   panel p = s>>1, rows (s&1)*64 + tid/4, k-off = p*32 + (tid&3)*8
  int srow = tid >> 2;         // 0..63
  int scol = (tid & 3) * 8;    // 0,8,16,24
  const u16* gA0 = &A[(long)(m0 + srow) * K + scol];
  const u16* gA1 = gA0 + (long)64 * K;
  const u16* gB0 = &Wt[(long)(n0 + srow) * K + scol];
  const u16* gB1 = gB0 + (long)64 * K;

  for (int k0 = 0; k0 < K; k0 += 64) {
    __syncthreads();  // prior LDS reads done before overwrite
    gld_lds16(gA0 + k0, &As[(size_t)tid * 8]);
    gld_lds16(gA1 + k0, &As[(size_t)(256 + tid) * 8]);
    gld_lds16(gA0 + k0 + 32, &As[(size_t)(512 + tid) * 8]);
    gld_lds16(gA1 + k0 + 32, &As[(size_t)(768 + tid) * 8]);
    gld_lds16(gB0 + k0, &Bs[(size_t)tid * 8]);
    gld_lds16(gB1 + k0, &Bs[(size_t)(256 + tid) * 8]);
    gld_lds16(gB0 + k0 + 32, &Bs[(size_t)(512 + tid) * 8]);
    gld_lds16(gB1 + k0 + 32, &Bs[(size_t)(768 + tid) * 8]);
    __syncthreads();  // drains vmcnt -> staged data visible

#pragma unroll
    for (int kk = 0; kk < 2; ++kk) {
      bf16x8 xf[4], wf[4];
#pragma unroll
      for (int t = 0; t < 4; ++t) {
        xf[t] = __builtin_bit_cast(bf16x8,
            *reinterpret_cast<u16x8*>(
                &As[kk * BM * 32 + (wm + t * 16 + col) * 32 + quad * 8]));
        wf[t] = __builtin_bit_cast(bf16x8,
            *reinterpret_cast<u16x8*>(
                &Bs[kk * BN * 32 + (wn + t * 16 + col) * 32 + quad * 8]));
      }
#pragma unroll
      for (int i = 0; i < 4; ++i)
#pragma unroll
        for (int j = 0; j < 4; ++j)
          acc[i][j] = __builtin_amdgcn_mfma_f32_16x16x32_bf16(
              wf[j], xf[i], acc[i][j], 0, 0, 0);
    }
  }

  // epilogue: lane holds m = m0+wm+i*16+col, n = n0+wn+j*16+quad*4+[0..3]
#pragma unroll
  for (int j = 0; j < 4; ++j) {
    int nn = n0 + wn + j * 16 + quad * 4;
    float4 b4 = *reinterpret_cast<const float4*>(&bias[nn]);
#pragma unroll
    for (int i = 0; i < 4; ++i) {
      int m = m0 + wm + i * 16 + col;
      u16x4 o;
      o.x = f2bf(elu1(acc[i][j][0] + b4.x));
      o.y = f2bf(elu1(acc[i][j][1] + b4.y));
      o.z = f2bf(elu1(acc[i][j][2] + b4.z));
      o.w = f2bf(elu1(acc[i][j][3] + b4.w));
      *reinterpret_cast<u16x4*>(&C[(long)m * N + nn]) = o;
    }
  }
}

// ---------------- fused L4: gate head + softmax + expert heads + combine ----
__global__ __launch_bounds__(64) void final_combine_kernel(
    const u16* __restrict__ h3, const u16* __restrict__ W4t,
    const u16* __restrict__ gW4t, const float* __restrict__ eb4,
    const float* __restrict__ gb4, float* __restrict__ out) {
  const int H3 = 256;
  int lane = threadIdx.x;
  int col = lane & 15;
  int quad = lane >> 4;
  int r0 = blockIdx.x * 16;

  // ---- gate logits ----
  floatx4 g0 = {}, g1 = {};
  const u16* h3g = h3 + (long)E_EXP * B_SZ * H3;
#pragma unroll
  for (int k0 = 0; k0 < 256; k0 += 32) {
    bf16x8 a = ld_bf8(&h3g[(long)(r0 + col) * H3 + k0 + quad * 8]);
    bf16x8 b0 = ld_bf8(&gW4t[(long)col * H3 + k0 + quad * 8]);
    bf16x8 b1 = ld_bf8(&gW4t[(long)(16 + col) * H3 + k0 + quad * 8]);
    g0 = __builtin_amdgcn_mfma_f32_16x16x32_bf16(a, b0, g0, 0, 0, 0);
    g1 = __builtin_amdgcn_mfma_f32_16x16x32_bf16(a, b1, g1, 0, 0, 0);
  }

  // ---- softmax over 20 logits per row ----
  float w0[4], w1[4];
  float gbc0 = gb4[col];
  float gbc1 = (col < 4) ? gb4[16 + col] : 0.f;
#pragma unroll
  for (int r = 0; r < 4; ++r) {
    float v0 = g0[r] + gbc0;
    float v1 = (col < 4) ? (g1[r] + gbc1) : -1e30f;
    float m = fmaxf(v0, v1);
#pragma unroll
    for (int s = 1; s < 16; s <<= 1) m = fmaxf(m, __shfl_xor(m, s, 64));
    float e0 = __expf(v0 - m);
    float e1 = (col < 4) ? __expf(v1 - m) : 0.f;
    float ssum = e0 + e1;
#pragma unroll
    for (int s = 1; s < 16; s <<= 1) ssum += __shfl_xor(ssum, s, 64);
    w0[r] = e0 / ssum;
    w1[r] = e1 / ssum;
  }

  // ---- expert heads + weighted combine ----
  floatx4 o0 = {}, o1 = {};
  for (int e = 0; e < E_EXP; ++e) {
    floatx4 a0 = {}, a1 = {};
    const u16* he = h3 + (long)e * B_SZ * H3;
    const u16* we = W4t + (long)e * 32 * H3;
#pragma unroll
    for (int k0 = 0; k0 < 256; k0 += 32) {
      bf16x8 a = ld_bf8(&he[(long)(r0 + col) * H3 + k0 + quad * 8]);
      bf16x8 b0 = ld_bf8(&we[(long)col * H3 + k0 + quad * 8]);
      bf16x8 b1 = ld_bf8(&we[(long)(16 + col) * H3 + k0 + quad * 8]);
      a0 = __builtin_amdgcn_mfma_f32_16x16x32_bf16(a, b0, a0, 0, 0, 0);
      a1 = __builtin_amdgcn_mfma_f32_16x16x32_bf16(a, b1, a1, 0, 0, 0);
    }
    float be0 = eb4[e * 32 + col];
    float be1 = eb4[e * 32 + 16 + col];
    int src = (lane & 48) + (e & 15);
#pragma unroll
    for (int r = 0; r < 4; ++r) {
      float wr = __shfl((e < 16) ? w0[r] : w1[r], src, 64);
      o0[r] += wr * (a0[r] + be0);
      o1[r] += wr * (a1[r] + be1);
    }
  }
#pragma unroll
  for (int r = 0; r < 4; ++r) {
    int row = r0 + quad * 4 + r;
    out[(long)row * 32 + col] = o0[r];
    out[(long)row * 32 + 16 + col] = o1[r];
  }
}

// ---------------- host launch ----------------

static inline size_t align256(size_t x) { return (x + 255) & ~(size_t)255; }

extern "C" void kernel_launch(void* const* d_in, const int* in_sizes, int n_in,
                              void* d_out, int out_size, void* d_ws,
                              size_t ws_size, hipStream_t stream) {
  const float* obs = (const float*)d_in[0];
  const float* eW1 = (const float*)d_in[1];
  const float* eb1 = (const float*)d_in[2];
  const float* eW2 = (const float*)d_in[3];
  const float* eb2 = (const float*)d_in[4];
  const float* eW3 = (const float*)d_in[5];
  const float* eb3 = (const float*)d_in[6];
  const float* eW4 = (const float*)d_in[7];
  const float* eb4 = (const float*)d_in[8];
  const float* gW1 = (const float*)d_in[9];
  const float* gb1 = (const float*)d_in[10];
  const float* gW2 = (const float*)d_in[11];
  const float* gb2 = (const float*)d_in[12];
  const float* gW3 = (const float*)d_in[13];
  const float* gb3 = (const float*)d_in[14];
  const float* gW4 = (const float*)d_in[15];
  const float* gb4 = (const float*)d_in[16];
  float* out = (float*)d_out;
  char* ws = (char*)d_ws;

  // fixed workspace region
  size_t off = 0;
  size_t OFF_OBS = off;  off = align256(off + (size_t)B_SZ * 512 * 2);
  size_t OFF_W1T = off;  off = align256(off + (size_t)NE * 1024 * 512 * 2);
  size_t OFF_W2T = off;  off = align256(off + (size_t)NE * 512 * 1024 * 2);
  size_t OFF_W3T = off;  off = align256(off + (size_t)NE * 256 * 512 * 2);
  size_t OFF_W4T = off;  off = align256(off + (size_t)E_EXP * 32 * 256 * 2);
  size_t OFF_GW4T = off; off = align256(off + (size_t)32 * 256 * 2);
  size_t OFF_B1 = off;   off = align256(off + (size_t)NE * 1024 * 4);
  size_t OFF_B2 = off;   off = align256(off + (size_t)NE * 512 * 4);
  size_t OFF_B3 = off;   off = align256(off + (size_t)NE * 256 * 4);
  size_t OFF_H3 = off;   off = align256(off + (size_t)NE * B_SZ * 256 * 2);

  // adaptive batch-chunked h1/h2: every dispatch covers all 21 experts
  int chunk = B_SZ;
  size_t OFF_H1 = off;
  while (chunk > 512) {
    size_t need = (size_t)NE * chunk * 1024 * 2 + (size_t)NE * chunk * 512 * 2;
    if (OFF_H1 + need <= ws_size) break;
    chunk >>= 1;
  }
  size_t OFF_H2 = align256(OFF_H1 + (size_t)NE * chunk * 1024 * 2);

  u16* obs_bf = (u16*)(ws + OFF_OBS);
  u16* W1t = (u16*)(ws + OFF_W1T);
  u16* W2t = (u16*)(ws + OFF_W2T);
  u16* W3t = (u16*)(ws + OFF_W3T);
  u16* W4t = (u16*)(ws + OFF_W4T);
  u16* gW4t = (u16*)(ws + OFF_GW4T);
  float* b1 = (float*)(ws + OFF_B1);
  float* b2 = (float*)(ws + OFF_B2);
  float* b3 = (float*)(ws + OFF_B3);
  u16* h3 = (u16*)(ws + OFF_H3);
  u16* h1 = (u16*)(ws + OFF_H1);
  u16* h2 = (u16*)(ws + OFF_H2);

  // --- conversions ---
  convert_obs_kernel<<<(B_SZ * 512 / 4 + 255) / 256, 256, 0, stream>>>(
      obs, obs_bf, B_SZ * 512);
  transpose_conv_kernel<<<dim3(16, 32, NE), 256, 0, stream>>>(
      eW1, gW1, E_EXP, 512, 1024, 1024, W1t);
  transpose_conv_kernel<<<dim3(32, 16, NE), 256, 0, stream>>>(
      eW2, gW2, E_EXP, 1024, 512, 512, W2t);
  transpose_conv_kernel<<<dim3(16, 8, NE), 256, 0, stream>>>(
      eW3, gW3, E_EXP, 512, 256, 256, W3t);
  transpose_conv_kernel<<<dim3(8, 1, E_EXP), 256, 0, stream>>>(
      eW4, nullptr, E_EXP, 256, 32, 32, W4t);
  transpose_conv_kernel<<<dim3(8, 1, 1), 256, 0, stream>>>(
      gW4, nullptr, 1, 256, 20, 32, gW4t);
  concat_bias_kernel<<<(NE * 1024 + 255) / 256, 256, 0, stream>>>(
      eb1, gb1, E_EXP, 1024, b1);
  concat_bias_kernel<<<(NE * 512 + 255) / 256, 256, 0, stream>>>(
      eb2, gb2, E_EXP, 512, b2);
  concat_bias_kernel<<<(NE * 256 + 255) / 256, 256, 0, stream>>>(
      eb3, gb3, E_EXP, 256, b3);

  // --- trunk layers 1..3, batch-chunked, all experts per dispatch ---
  for (int bc = 0; bc < B_SZ; bc += chunk) {
    gemm_bias_elu_kernel<<<dim3(1024 / BN, chunk / BM, NE), 256, 0, stream>>>(
        obs_bf + (size_t)bc * 512, 0L,
        W1t, (long)1024 * 512,
        b1, 1024L,
        h1, (long)chunk * 1024, chunk, 1024, 512);
    gemm_bias_elu_kernel<<<dim3(512 / BN, chunk / BM, NE), 256, 0, stream>>>(
        h1, (long)chunk * 1024,
        W2t, (long)512 * 1024,
        b2, 512L,
        h2, (long)chunk * 512, chunk, 512, 1024);
    gemm_bias_elu_kernel<<<dim3(256 / BN, chunk / BM, NE), 256, 0, stream>>>(
        h2, (long)chunk * 512,
        W3t, (long)256 * 512,
        b3, 256L,
        h3 + (size_t)bc * 256, (long)B_SZ * 256, chunk, 256, 512);
  }

  // --- fused layer-4 + softmax + combine ---
  final_combine_kernel<<<B_SZ / 16, 64, 0, stream>>>(h3, W4t, gW4t, eb4, gb4,
                                                     out);
}

// Round 5
// 551.355 us; speedup vs baseline: 1.2712x; 1.0287x over previous
//
#include <hip/hip_runtime.h>

#define B_SZ 4096
#define E_EXP 20
#define NE 21  // 20 experts + gate share the trunk

typedef unsigned short u16;
typedef __bf16 bf16x8 __attribute__((ext_vector_type(8)));
typedef u16 u16x8 __attribute__((ext_vector_type(8)));
typedef u16 u16x4 __attribute__((ext_vector_type(4)));
typedef float floatx4 __attribute__((ext_vector_type(4)));

static __device__ __forceinline__ u16 f2bf(float f) {
  unsigned u = __builtin_bit_cast(unsigned, f);
  u += 0x7fffu + ((u >> 16) & 1u);  // RNE
  return (u16)(u >> 16);
}

static __device__ __forceinline__ float elu1(float v) {
  return v > 0.f ? v : (__expf(v) - 1.f);
}

static __device__ __forceinline__ bf16x8 ld_bf8(const u16* p) {
  u16x8 v = *reinterpret_cast<const u16x8*>(p);
  return __builtin_bit_cast(bf16x8, v);
}

// async global->LDS DMA, 16B per lane. LDS dest is wave-uniform base +
// lane*16 — lds ptr must be linear in thread order (no padding!).
static __device__ __forceinline__ void gld_lds16(const u16* g, u16* l) {
  __builtin_amdgcn_global_load_lds(
      (const __attribute__((address_space(1))) unsigned int*)g,
      (__attribute__((address_space(3))) unsigned int*)l, 16, 0, 0);
}

// ---------------- conversion kernels ----------------

__global__ void convert_obs_kernel(const float* __restrict__ src,
                                   u16* __restrict__ dst, int n) {
  int i = (blockIdx.x * blockDim.x + threadIdx.x) * 4;
  if (i < n) {
    float4 v = *reinterpret_cast<const float4*>(src + i);
    u16x4 o;
    o.x = f2bf(v.x); o.y = f2bf(v.y); o.z = f2bf(v.z); o.w = f2bf(v.w);
    *reinterpret_cast<u16x4*>(dst + i) = o;
  }
}

// W [K,N] fp32 -> Wt [N(out-padded),K] bf16, per blockIdx.z matrix.
// 64x64 tile via LDS: float4 coalesced reads (256B), u16x8 row writes (128B).
__global__ __launch_bounds__(256) void transpose_conv_kernel(
    const float* __restrict__ src_e, const float* __restrict__ src_g,
    int n_e, int K, int N, int Nout, u16* __restrict__ dst) {
  int e = blockIdx.z;
  const float* src = (e < n_e) ? (src_e + (long)e * K * N) : src_g;
  __shared__ float t[64][65];
  int tid = threadIdx.x;
  int kbase = blockIdx.x * 64;
  int nbase = blockIdx.y * 64;

  int kk = tid >> 4;        // 0..15
  int n4 = (tid & 15) * 4;  // 0..60
#pragma unroll
  for (int p = 0; p < 4; ++p) {
    int k = kbase + p * 16 + kk;  // always < K (grid exact)
    int n = nbase + n4;
    float4 v = make_float4(0.f, 0.f, 0.f, 0.f);
    if (n + 3 < N) {
      v = *reinterpret_cast<const float4*>(&src[(long)k * N + n]);
    } else {
      float* vp = &v.x;
      for (int j = 0; j < 4; ++j)
        if (n + j < N) vp[j] = src[(long)k * N + n + j];
    }
    t[p * 16 + kk][n4 + 0] = v.x;
    t[p * 16 + kk][n4 + 1] = v.y;
    t[p * 16 + kk][n4 + 2] = v.z;
    t[p * 16 + kk][n4 + 3] = v.w;
  }
  __syncthreads();

  u16* dstE = dst + (long)e * Nout * K;
  int kk8 = (tid & 7) * 8;
#pragma unroll
  for (int p = 0; p < 2; ++p) {
    int ln = p * 32 + (tid >> 3);  // 0..63
    int n = nbase + ln;
    if (n < Nout) {
      u16x8 o;
#pragma unroll
      for (int j = 0; j < 8; ++j) o[j] = f2bf(t[kk8 + j][ln]);
      *reinterpret_cast<u16x8*>(&dstE[(long)n * K + kbase + kk8]) = o;
    }
  }
}

// concat all 3 trunk biases in one dispatch: [E,H]+[H] -> [E+1,H] each
__global__ void concat_bias3_kernel(
    const float* __restrict__ eb1, const float* __restrict__ gb1,
    const float* __restrict__ eb2, const float* __restrict__ gb2,
    const float* __restrict__ eb3, const float* __restrict__ gb3,
    float* __restrict__ b1, float* __restrict__ b2, float* __restrict__ b3) {
  int i = blockIdx.x * blockDim.x + threadIdx.x;
  const int S1 = NE * 1024, S2 = NE * 512, S3 = NE * 256;
  if (i < S1) {
    b1[i] = (i < E_EXP * 1024) ? eb1[i] : gb1[i - E_EXP * 1024];
  } else if (i < S1 + S2) {
    int j = i - S1;
    b2[j] = (j < E_EXP * 512) ? eb2[j] : gb2[j - E_EXP * 512];
  } else if (i < S1 + S2 + S3) {
    int j = i - S1 - S2;
    b3[j] = (j < E_EXP * 256) ? eb3[j] : gb3[j - E_EXP * 256];
  }
}

// ---------------- grouped GEMM + bias + ELU (unchanged from R4) ----------
#define BM 128
#define BN 128

__global__ __launch_bounds__(256) void gemm_bias_elu_kernel(
    const u16* __restrict__ A_base, long a_estride,
    const u16* __restrict__ Wt_base, long w_estride,
    const float* __restrict__ bias_base, long b_estride,
    u16* __restrict__ C_base, long c_estride,
    int M, int N, int K) {
  int e = blockIdx.z;
  const u16* A = A_base + (long)e * a_estride;
  const u16* Wt = Wt_base + (long)e * w_estride;
  const float* bias = bias_base + (long)e * b_estride;
  u16* C = C_base + (long)e * c_estride;

  int m0 = blockIdx.y * BM;
  int n0 = blockIdx.x * BN;

  // [panel][row][32] — lane-linear for global_load_lds (no padding)
  __shared__ u16 As[2 * BM * 32];
  __shared__ u16 Bs[2 * BN * 32];

  int tid = threadIdx.x;
  int lane = tid & 63;
  int w = tid >> 6;            // wave 0..3 in 2x2
  int wm = (w >> 1) * 64;
  int wn = (w & 1) * 64;
  int col = lane & 15;
  int quad = lane >> 4;

  floatx4 acc[4][4] = {};

  int srow = tid >> 2;         // 0..63
  int scol = (tid & 3) * 8;    // 0,8,16,24
  const u16* gA0 = &A[(long)(m0 + srow) * K + scol];
  const u16* gA1 = gA0 + (long)64 * K;
  const u16* gB0 = &Wt[(long)(n0 + srow) * K + scol];
  const u16* gB1 = gB0 + (long)64 * K;

  for (int k0 = 0; k0 < K; k0 += 64) {
    __syncthreads();  // prior LDS reads done before overwrite
    gld_lds16(gA0 + k0, &As[(size_t)tid * 8]);
    gld_lds16(gA1 + k0, &As[(size_t)(256 + tid) * 8]);
    gld_lds16(gA0 + k0 + 32, &As[(size_t)(512 + tid) * 8]);
    gld_lds16(gA1 + k0 + 32, &As[(size_t)(768 + tid) * 8]);
    gld_lds16(gB0 + k0, &Bs[(size_t)tid * 8]);
    gld_lds16(gB1 + k0, &Bs[(size_t)(256 + tid) * 8]);
    gld_lds16(gB0 + k0 + 32, &Bs[(size_t)(512 + tid) * 8]);
    gld_lds16(gB1 + k0 + 32, &Bs[(size_t)(768 + tid) * 8]);
    __syncthreads();  // drains vmcnt -> staged data visible

#pragma unroll
    for (int kk = 0; kk < 2; ++kk) {
      bf16x8 xf[4], wf[4];
#pragma unroll
      for (int t = 0; t < 4; ++t) {
        xf[t] = __builtin_bit_cast(bf16x8,
            *reinterpret_cast<u16x8*>(
                &As[kk * BM * 32 + (wm + t * 16 + col) * 32 + quad * 8]));
        wf[t] = __builtin_bit_cast(bf16x8,
            *reinterpret_cast<u16x8*>(
                &Bs[kk * BN * 32 + (wn + t * 16 + col) * 32 + quad * 8]));
      }
#pragma unroll
      for (int i = 0; i < 4; ++i)
#pragma unroll
        for (int j = 0; j < 4; ++j)
          acc[i][j] = __builtin_amdgcn_mfma_f32_16x16x32_bf16(
              wf[j], xf[i], acc[i][j], 0, 0, 0);
    }
  }

  // epilogue: lane holds m = m0+wm+i*16+col, n = n0+wn+j*16+quad*4+[0..3]
#pragma unroll
  for (int j = 0; j < 4; ++j) {
    int nn = n0 + wn + j * 16 + quad * 4;
    float4 b4 = *reinterpret_cast<const float4*>(&bias[nn]);
#pragma unroll
    for (int i = 0; i < 4; ++i) {
      int m = m0 + wm + i * 16 + col;
      u16x4 o;
      o.x = f2bf(elu1(acc[i][j][0] + b4.x));
      o.y = f2bf(elu1(acc[i][j][1] + b4.y));
      o.z = f2bf(elu1(acc[i][j][2] + b4.z));
      o.w = f2bf(elu1(acc[i][j][3] + b4.w));
      *reinterpret_cast<u16x4*>(&C[(long)m * N + nn]) = o;
    }
  }
}

// ---------------- fused L4: gate + softmax + expert heads + combine -------
// 4 waves/block: each wave computes gate logits (redundant, cheap) then
// handles experts {w, w+4, ...}; partials reduced through LDS.
__global__ __launch_bounds__(256) void final_combine_kernel(
    const u16* __restrict__ h3, const u16* __restrict__ W4t,
    const u16* __restrict__ gW4t, const float* __restrict__ eb4,
    const float* __restrict__ gb4, float* __restrict__ out) {
  const int H3 = 256;
  int tid = threadIdx.x;
  int lane = tid & 63;
  int w = tid >> 6;  // wave 0..3
  int col = lane & 15;
  int quad = lane >> 4;
  int r0 = blockIdx.x * 16;

  // ---- gate logits (every wave, same 16 rows) ----
  floatx4 g0 = {}, g1 = {};
  const u16* h3g = h3 + (long)E_EXP * B_SZ * H3;
#pragma unroll
  for (int k0 = 0; k0 < 256; k0 += 32) {
    bf16x8 a = ld_bf8(&h3g[(long)(r0 + col) * H3 + k0 + quad * 8]);
    bf16x8 b0 = ld_bf8(&gW4t[(long)col * H3 + k0 + quad * 8]);
    bf16x8 b1 = ld_bf8(&gW4t[(long)(16 + col) * H3 + k0 + quad * 8]);
    g0 = __builtin_amdgcn_mfma_f32_16x16x32_bf16(a, b0, g0, 0, 0, 0);
    g1 = __builtin_amdgcn_mfma_f32_16x16x32_bf16(a, b1, g1, 0, 0, 0);
  }

  // ---- softmax over 20 logits per row ----
  float w0[4], w1[4];
  float gbc0 = gb4[col];
  float gbc1 = (col < 4) ? gb4[16 + col] : 0.f;
#pragma unroll
  for (int r = 0; r < 4; ++r) {
    float v0 = g0[r] + gbc0;
    float v1 = (col < 4) ? (g1[r] + gbc1) : -1e30f;
    float m = fmaxf(v0, v1);
#pragma unroll
    for (int s = 1; s < 16; s <<= 1) m = fmaxf(m, __shfl_xor(m, s, 64));
    float e0 = __expf(v0 - m);
    float e1 = (col < 4) ? __expf(v1 - m) : 0.f;
    float ssum = e0 + e1;
#pragma unroll
    for (int s = 1; s < 16; s <<= 1) ssum += __shfl_xor(ssum, s, 64);
    w0[r] = e0 / ssum;
    w1[r] = e1 / ssum;
  }

  // ---- this wave's experts: w, w+4, w+8, w+12, w+16 ----
  floatx4 o0 = {}, o1 = {};
  for (int e = w; e < E_EXP; e += 4) {
    floatx4 a0 = {}, a1 = {};
    const u16* he = h3 + (long)e * B_SZ * H3;
    const u16* we = W4t + (long)e * 32 * H3;
#pragma unroll
    for (int k0 = 0; k0 < 256; k0 += 32) {
      bf16x8 a = ld_bf8(&he[(long)(r0 + col) * H3 + k0 + quad * 8]);
      bf16x8 b0 = ld_bf8(&we[(long)col * H3 + k0 + quad * 8]);
      bf16x8 b1 = ld_bf8(&we[(long)(16 + col) * H3 + k0 + quad * 8]);
      a0 = __builtin_amdgcn_mfma_f32_16x16x32_bf16(a, b0, a0, 0, 0, 0);
      a1 = __builtin_amdgcn_mfma_f32_16x16x32_bf16(a, b1, a1, 0, 0, 0);
    }
    float be0 = eb4[e * 32 + col];
    float be1 = eb4[e * 32 + 16 + col];
    int src = (lane & 48) + (e & 15);
#pragma unroll
    for (int r = 0; r < 4; ++r) {
      float wr = __shfl((e < 16) ? w0[r] : w1[r], src, 64);
      o0[r] += wr * (a0[r] + be0);
      o1[r] += wr * (a1[r] + be1);
    }
  }

  // ---- cross-wave reduce in LDS ----
  __shared__ float red[3][64][8];
  if (w > 0) {
#pragma unroll
    for (int r = 0; r < 4; ++r) {
      red[w - 1][lane][r] = o0[r];
      red[w - 1][lane][4 + r] = o1[r];
    }
  }
  __syncthreads();
  if (w == 0) {
#pragma unroll
    for (int ww = 0; ww < 3; ++ww)
#pragma unroll
      for (int r = 0; r < 4; ++r) {
        o0[r] += red[ww][lane][r];
        o1[r] += red[ww][lane][4 + r];
      }
#pragma unroll
    for (int r = 0; r < 4; ++r) {
      int row = r0 + quad * 4 + r;
      out[(long)row * 32 + col] = o0[r];
      out[(long)row * 32 + 16 + col] = o1[r];
    }
  }
}

// ---------------- host launch ----------------

static inline size_t align256(size_t x) { return (x + 255) & ~(size_t)255; }

extern "C" void kernel_launch(void* const* d_in, const int* in_sizes, int n_in,
                              void* d_out, int out_size, void* d_ws,
                              size_t ws_size, hipStream_t stream) {
  const float* obs = (const float*)d_in[0];
  const float* eW1 = (const float*)d_in[1];
  const float* eb1 = (const float*)d_in[2];
  const float* eW2 = (const float*)d_in[3];
  const float* eb2 = (const float*)d_in[4];
  const float* eW3 = (const float*)d_in[5];
  const float* eb3 = (const float*)d_in[6];
  const float* eW4 = (const float*)d_in[7];
  const float* eb4 = (const float*)d_in[8];
  const float* gW1 = (const float*)d_in[9];
  const float* gb1 = (const float*)d_in[10];
  const float* gW2 = (const float*)d_in[11];
  const float* gb2 = (const float*)d_in[12];
  const float* gW3 = (const float*)d_in[13];
  const float* gb3 = (const float*)d_in[14];
  const float* gW4 = (const float*)d_in[15];
  const float* gb4 = (const float*)d_in[16];
  float* out = (float*)d_out;
  char* ws = (char*)d_ws;

  // fixed workspace region
  size_t off = 0;
  size_t OFF_OBS = off;  off = align256(off + (size_t)B_SZ * 512 * 2);
  size_t OFF_W1T = off;  off = align256(off + (size_t)NE * 1024 * 512 * 2);
  size_t OFF_W2T = off;  off = align256(off + (size_t)NE * 512 * 1024 * 2);
  size_t OFF_W3T = off;  off = align256(off + (size_t)NE * 256 * 512 * 2);
  size_t OFF_W4T = off;  off = align256(off + (size_t)E_EXP * 32 * 256 * 2);
  size_t OFF_GW4T = off; off = align256(off + (size_t)32 * 256 * 2);
  size_t OFF_B1 = off;   off = align256(off + (size_t)NE * 1024 * 4);
  size_t OFF_B2 = off;   off = align256(off + (size_t)NE * 512 * 4);
  size_t OFF_B3 = off;   off = align256(off + (size_t)NE * 256 * 4);
  size_t OFF_H3 = off;   off = align256(off + (size_t)NE * B_SZ * 256 * 2);

  // adaptive batch-chunked h1/h2: every dispatch covers all 21 experts
  int chunk = B_SZ;
  size_t OFF_H1 = off;
  while (chunk > 512) {
    size_t need = (size_t)NE * chunk * 1024 * 2 + (size_t)NE * chunk * 512 * 2;
    if (OFF_H1 + need <= ws_size) break;
    chunk >>= 1;
  }
  size_t OFF_H2 = align256(OFF_H1 + (size_t)NE * chunk * 1024 * 2);

  u16* obs_bf = (u16*)(ws + OFF_OBS);
  u16* W1t = (u16*)(ws + OFF_W1T);
  u16* W2t = (u16*)(ws + OFF_W2T);
  u16* W3t = (u16*)(ws + OFF_W3T);
  u16* W4t = (u16*)(ws + OFF_W4T);
  u16* gW4t = (u16*)(ws + OFF_GW4T);
  float* b1 = (float*)(ws + OFF_B1);
  float* b2 = (float*)(ws + OFF_B2);
  float* b3 = (float*)(ws + OFF_B3);
  u16* h3 = (u16*)(ws + OFF_H3);
  u16* h1 = (u16*)(ws + OFF_H1);
  u16* h2 = (u16*)(ws + OFF_H2);

  // --- conversions ---
  convert_obs_kernel<<<(B_SZ * 512 / 4 + 255) / 256, 256, 0, stream>>>(
      obs, obs_bf, B_SZ * 512);
  transpose_conv_kernel<<<dim3(8, 16, NE), 256, 0, stream>>>(
      eW1, gW1, E_EXP, 512, 1024, 1024, W1t);
  transpose_conv_kernel<<<dim3(16, 8, NE), 256, 0, stream>>>(
      eW2, gW2, E_EXP, 1024, 512, 512, W2t);
  transpose_conv_kernel<<<dim3(8, 4, NE), 256, 0, stream>>>(
      eW3, gW3, E_EXP, 512, 256, 256, W3t);
  transpose_conv_kernel<<<dim3(4, 1, E_EXP), 256, 0, stream>>>(
      eW4, nullptr, E_EXP, 256, 32, 32, W4t);
  transpose_conv_kernel<<<dim3(4, 1, 1), 256, 0, stream>>>(
      gW4, nullptr, 1, 256, 20, 32, gW4t);
  concat_bias3_kernel<<<(NE * 1792 + 255) / 256, 256, 0, stream>>>(
      eb1, gb1, eb2, gb2, eb3, gb3, b1, b2, b3);

  // --- trunk layers 1..3, batch-chunked, all experts per dispatch ---
  for (int bc = 0; bc < B_SZ; bc += chunk) {
    gemm_bias_elu_kernel<<<dim3(1024 / BN, chunk / BM, NE), 256, 0, stream>>>(
        obs_bf + (size_t)bc * 512, 0L,
        W1t, (long)1024 * 512,
        b1, 1024L,
        h1, (long)chunk * 1024, chunk, 1024, 512);
    gemm_bias_elu_kernel<<<dim3(512 / BN, chunk / BM, NE), 256, 0, stream>>>(
        h1, (long)chunk * 1024,
        W2t, (long)512 * 1024,
        b2, 512L,
        h2, (long)chunk * 512, chunk, 512, 1024);
    gemm_bias_elu_kernel<<<dim3(256 / BN, chunk / BM, NE), 256, 0, stream>>>(
        h2, (long)chunk * 512,
        W3t, (long)256 * 512,
        b3, 256L,
        h3 + (size_t)bc * 256, (long)B_SZ * 256, chunk, 256, 512);
  }

  // --- fused layer-4 + softmax + combine ---
  final_combine_kernel<<<B_SZ / 16, 256, 0, stream>>>(h3, W4t, gW4t, eb4, gb4,
                                                      out);
}